// Round 1
// baseline (22465.471 us; speedup 1.0000x reference)
//
#include <hip/hip_runtime.h>

#define NN 50000
#define NE 800000
#define D 128
#define HE 32
#define HEADS 4
#define DEPTH 8
#define EPSV 1e-5f
#define SLOPE 0.01f

__device__ __forceinline__ float lrelu(float x) { return x > 0.f ? x : SLOPE * x; }

// ---------- h init: h = concat(Wseq[seq], Wsec[sec]) ----------
__global__ void k_init_h(const int* __restrict__ seq, const int* __restrict__ sec,
                         const float* __restrict__ Wseq, const float* __restrict__ Wsec,
                         float* __restrict__ h) {
    int n = blockIdx.x;
    int d = threadIdx.x;  // 128
    float v = (d < 96) ? Wseq[seq[n] * 96 + d] : Wsec[sec[n] * 32 + (d - 96)];
    h[(size_t)n * D + d] = v;
}

// ---------- CSR build ----------
__global__ void k_count(const int* __restrict__ dst, int* __restrict__ cnt) {
    int e = blockIdx.x * blockDim.x + threadIdx.x;
    if (e < NE) atomicAdd(&cnt[dst[e]], 1);
}

__global__ void k_scan(const int* __restrict__ cnt, int* __restrict__ indptr) {
    __shared__ int sh[257];
    const int T = 256;
    int tid = threadIdx.x;
    int chunk = (NN + T - 1) / T;
    int b = tid * chunk;
    int e = min(b + chunk, NN);
    int s = 0;
    for (int i = b; i < e; i++) s += cnt[i];
    sh[tid] = s;
    __syncthreads();
    if (tid == 0) {
        int run = 0;
        for (int i = 0; i < T; i++) { int v = sh[i]; sh[i] = run; run += v; }
        sh[256] = run;
    }
    __syncthreads();
    int run = sh[tid];
    for (int i = b; i < e; i++) { indptr[i] = run; run += cnt[i]; }
    if (tid == 0) indptr[NN] = sh[256];
}

__global__ void k_scatter(const int* __restrict__ dst, const int* __restrict__ indptr,
                          int* __restrict__ cursor, int* __restrict__ esort) {
    int e = blockIdx.x * blockDim.x + threadIdx.x;
    if (e >= NE) return;
    int dn = dst[e];
    int pos = atomicAdd(&cursor[dn], 1);
    esort[indptr[dn] + pos] = e;
}

// ---------- Layer-0 edge kernel (heads=1, e is scalar edge_p) ----------
__global__ __launch_bounds__(256) void k_edge0(
    const float* __restrict__ h, const float* __restrict__ edge_p,
    const int* __restrict__ src, const int* __restrict__ dst,
    const float* __restrict__ Wni, const float* __restrict__ Wfij,
    const float* __restrict__ Wnj, const float* __restrict__ attn,
    const float* __restrict__ ebias, float* __restrict__ fout,
    float* __restrict__ logits) {
    int e = blockIdx.x * blockDim.x + threadIdx.x;
    if (e >= NE) return;
    int sn = src[e], dn = dst[e];
    const float* hs = h + (size_t)sn * D;
    const float* hd = h + (size_t)dn * D;
    float p = edge_p[e];
    float acc[HE];
#pragma unroll
    for (int k = 0; k < HE; k++) acc[k] = ebias[k] + p * Wfij[k];
    for (int d = 0; d < D; d++) {
        float a = hs[d], b = hd[d];
#pragma unroll
        for (int k = 0; k < HE; k++) acc[k] += a * Wni[d * HE + k] + b * Wnj[d * HE + k];
    }
    float lg = 0.f;
#pragma unroll
    for (int k = 0; k < HE; k++) {
        acc[k] = lrelu(acc[k]);
        lg += acc[k] * attn[k];
    }
    float4* fo = (float4*)(fout + (size_t)e * HE);
#pragma unroll
    for (int j = 0; j < HE / 4; j++) {
        float4 v = make_float4(acc[4 * j], acc[4 * j + 1], acc[4 * j + 2], acc[4 * j + 3]);
        fo[j] = v;
    }
    logits[e] = lg;
}

// ---------- Deep-layer edge kernel (heads=4, e is (E,32), in-place f) ----------
__global__ __launch_bounds__(256) void k_edgeB(
    const float* __restrict__ h, const float* __restrict__ e_in,
    const int* __restrict__ src, const int* __restrict__ dst,
    const float* __restrict__ Wni, const float* __restrict__ Wfij,
    const float* __restrict__ Wnj, const float* __restrict__ attn,
    const float* __restrict__ ebias, float* __restrict__ fout,
    float* __restrict__ logits) {
    int e = blockIdx.x * blockDim.x + threadIdx.x;
    if (e >= NE) return;
    int sn = src[e], dn = dst[e];
    const float* hs = h + (size_t)sn * D;
    const float* hd = h + (size_t)dn * D;
    float er[HE];
    const float4* ei = (const float4*)(e_in + (size_t)e * HE);
#pragma unroll
    for (int j = 0; j < HE / 4; j++) {
        float4 v = ei[j];
        er[4 * j] = v.x; er[4 * j + 1] = v.y; er[4 * j + 2] = v.z; er[4 * j + 3] = v.w;
    }
    float acc[HE];
#pragma unroll
    for (int k = 0; k < HE; k++) acc[k] = ebias[k];
    for (int de = 0; de < HE; de++) {
        float ev = er[de];
#pragma unroll
        for (int k = 0; k < HE; k++) acc[k] += ev * Wfij[de * HE + k];
    }
    for (int d = 0; d < D; d++) {
        float a = hs[d], b = hd[d];
#pragma unroll
        for (int k = 0; k < HE; k++) acc[k] += a * Wni[d * HE + k] + b * Wnj[d * HE + k];
    }
#pragma unroll
    for (int k = 0; k < HE; k++) acc[k] = lrelu(acc[k]);
    float4* fo = (float4*)(fout + (size_t)e * HE);
#pragma unroll
    for (int j = 0; j < HE / 4; j++) {
        float4 v = make_float4(acc[4 * j], acc[4 * j + 1], acc[4 * j + 2], acc[4 * j + 3]);
        fo[j] = v;
    }
#pragma unroll
    for (int hh = 0; hh < HEADS; hh++) {
        float lg = 0.f;
#pragma unroll
        for (int j = 0; j < 8; j++) lg += acc[hh * 8 + j] * attn[hh * 8 + j];
        logits[(size_t)e * HEADS + hh] = lg;
    }
}

// ---------- per-(dst,head) segment softmax over CSR, in-place ----------
template <int H>
__global__ void k_softmax(const int* __restrict__ indptr, const int* __restrict__ esort,
                          float* __restrict__ logits) {
    int t = blockIdx.x * blockDim.x + threadIdx.x;
    int n = t / H;
    int hh = t % H;
    if (n >= NN) return;
    int b = indptr[n], e = indptr[n + 1];
    if (b == e) return;
    float m = -1e30f;
    for (int i = b; i < e; i++) {
        float v = logits[(size_t)esort[i] * H + hh];
        m = fmaxf(m, v);
    }
    float s = 0.f;
    for (int i = b; i < e; i++) s += expf(logits[(size_t)esort[i] * H + hh] - m);
    float inv = 1.f / s;
    for (int i = b; i < e; i++) {
        size_t idx = (size_t)esort[i] * H + hh;
        logits[idx] = expf(logits[idx] - m) * inv;
    }
}

// ---------- hp = h @ W + b  (N x D) ----------
__global__ __launch_bounds__(256) void k_matmul_hp(const float* __restrict__ h,
                                                   const float* __restrict__ W,
                                                   const float* __restrict__ bias,
                                                   float* __restrict__ hp) {
    int t = blockIdx.x * blockDim.x + threadIdx.x;
    int n = t / (D / 4);
    int c0 = (t % (D / 4)) * 4;
    if (n >= NN) return;
    const float* hr = h + (size_t)n * D;
    float4 acc = *(const float4*)(bias + c0);
    for (int d = 0; d < D; d++) {
        float hv = hr[d];
        float4 w = *(const float4*)(W + (size_t)d * D + c0);
        acc.x += hv * w.x; acc.y += hv * w.y; acc.z += hv * w.z; acc.w += hv * w.w;
    }
    *(float4*)(hp + (size_t)n * D + c0) = acc;
}

// ---------- h_out[n][d] = sum_{in edges} a[e][d/32] * hp[src[e]][d] ----------
template <int H>
__global__ void k_aggregate(const int* __restrict__ indptr, const int* __restrict__ esort,
                            const int* __restrict__ src, const float* __restrict__ a,
                            const float* __restrict__ hp, float* __restrict__ hacc) {
    int n = blockIdx.x;
    int d = threadIdx.x;  // 128
    int b = indptr[n], e = indptr[n + 1];
    int hh = (H == 1) ? 0 : (d >> 5);
    float acc = 0.f;
    for (int i = b; i < e; i++) {
        int eid = esort[i];
        float av = a[(size_t)eid * H + hh];
        acc += av * hp[(size_t)src[eid] * D + d];
    }
    hacc[(size_t)n * D + d] = acc;
}

// ---------- batchnorm stats: sums[d], sums[C+d] = sum, sumsq ----------
template <int C>
__global__ void k_bnstats(const float* __restrict__ x, int rows, float* __restrict__ sums) {
    int d = threadIdx.x;  // C
    float s = 0.f, s2 = 0.f;
    for (int r = blockIdx.x; r < rows; r += gridDim.x) {
        float v = x[(size_t)r * C + d];
        s += v;
        s2 += v * v;
    }
    atomicAdd(&sums[d], s);
    atomicAdd(&sums[C + d], s2);
}

// ---------- batchnorm apply + leaky_relu ----------
template <int C>
__global__ void k_bnapply(const float* __restrict__ x, const float* __restrict__ sums,
                          const float* __restrict__ gamma, const float* __restrict__ beta,
                          float* __restrict__ y, int rows) {
    long t = (long)blockIdx.x * blockDim.x + threadIdx.x;
    if (t >= (long)rows * C) return;
    int d = (int)(t % C);
    float inv_r = 1.f / rows;
    float mu = sums[d] * inv_r;
    float var = sums[C + d] * inv_r - mu * mu;
    float sc = rsqrtf(var + EPSV) * gamma[d];
    float v = (x[t] - mu) * sc + beta[d];
    y[t] = lrelu(v);
}

// ---------- out = h @ Wfc + bfc ----------
__global__ void k_out(const float* __restrict__ h, const float* __restrict__ Wfc,
                      const float* __restrict__ bfc, float* __restrict__ out) {
    int n = blockIdx.x * blockDim.x + threadIdx.x;
    if (n >= NN) return;
    const float* hr = h + (size_t)n * D;
    float s = bfc[0];
    for (int d = 0; d < D; d++) s += hr[d] * Wfc[d];
    out[n] = s;
}

extern "C" void kernel_launch(void* const* d_in, const int* in_sizes, int n_in,
                              void* d_out, int out_size, void* d_ws, size_t ws_size,
                              hipStream_t stream) {
    const int* seq = (const int*)d_in[0];
    const int* sec = (const int*)d_in[1];
    const float* edge_p = (const float*)d_in[2];
    const int* src = (const int*)d_in[3];
    const int* dst = (const int*)d_in[4];
    const float* Wseq = (const float*)d_in[5];
    const float* Wsec = (const float*)d_in[6];
    const float* W0_node = (const float*)d_in[7];
    const float* b0_node = (const float*)d_in[8];
    const float* W0_ni = (const float*)d_in[9];
    const float* W0_fij = (const float*)d_in[10];
    const float* W0_nj = (const float*)d_in[11];
    const float* attn0 = (const float*)d_in[12];
    const float* ebias0 = (const float*)d_in[13];
    const float* Wn = (const float*)d_in[14];
    const float* bn = (const float*)d_in[15];
    const float* Wni = (const float*)d_in[16];
    const float* Wfij = (const float*)d_in[17];
    const float* Wnj = (const float*)d_in[18];
    const float* attnB = (const float*)d_in[19];
    const float* ebiasB = (const float*)d_in[20];
    const float* gn = (const float*)d_in[21];
    const float* betan = (const float*)d_in[22];
    const float* ge = (const float*)d_in[23];
    const float* betae = (const float*)d_in[24];
    const float* Wfc = (const float*)d_in[25];
    const float* bfc = (const float*)d_in[26];

    char* p = (char*)d_ws;
    auto alloc = [&](size_t bytes) -> char* {
        char* r = p;
        p += (bytes + 255) & ~(size_t)255;
        return r;
    };
    float* hA = (float*)alloc((size_t)NN * D * 4);       // layer0 h / deep-layer agg tmp
    float* hB = (float*)alloc((size_t)NN * D * 4);       // running h
    float* hp = (float*)alloc((size_t)NN * D * 4);
    float* ebuf = (float*)alloc((size_t)NE * HE * 4);    // e / f (in-place)
    float* logits = (float*)alloc((size_t)NE * HEADS * 4);
    int* cnt = (int*)alloc((size_t)NN * 4);
    int* cursor = (int*)alloc((size_t)NN * 4);
    int* indptr = (int*)alloc((size_t)(NN + 1) * 4);
    int* esort = (int*)alloc((size_t)NE * 4);
    float* stats = (float*)alloc(320 * 4);  // [0..255] h stats, [256..319] e stats
    float* statsH = stats;
    float* statsE = stats + 256;

    const int EB = (NE + 255) / 256;  // 3125

    // CSR build
    hipMemsetAsync(cnt, 0, (size_t)NN * 4, stream);
    hipMemsetAsync(cursor, 0, (size_t)NN * 4, stream);
    k_init_h<<<NN, 128, 0, stream>>>(seq, sec, Wseq, Wsec, hA);
    k_count<<<EB, 256, 0, stream>>>(dst, cnt);
    k_scan<<<1, 256, 0, stream>>>(cnt, indptr);
    k_scatter<<<EB, 256, 0, stream>>>(dst, indptr, cursor, esort);

    // ---- layer 0 (heads = 1), no BN ----
    k_edge0<<<EB, 256, 0, stream>>>(hA, edge_p, src, dst, W0_ni, W0_fij, W0_nj, attn0,
                                    ebias0, ebuf, logits);
    k_softmax<1><<<(NN + 255) / 256, 256, 0, stream>>>(indptr, esort, logits);
    k_matmul_hp<<<(NN * (D / 4) + 255) / 256, 256, 0, stream>>>(hA, W0_node, b0_node, hp);
    k_aggregate<1><<<NN, 128, 0, stream>>>(indptr, esort, src, logits, hp, hB);

    // ---- deep layers ----
    for (int l = 0; l < DEPTH; l++) {
        const float* Wn_l = Wn + (size_t)l * D * D;
        const float* bn_l = bn + (size_t)l * D;
        const float* Wni_l = Wni + (size_t)l * D * HE;
        const float* Wfij_l = Wfij + (size_t)l * HE * HE;
        const float* Wnj_l = Wnj + (size_t)l * D * HE;
        const float* attn_l = attnB + (size_t)l * HEADS * (HE / HEADS);
        const float* eb_l = ebiasB + (size_t)l * HE;
        const float* gn_l = gn + (size_t)l * D;
        const float* btn_l = betan + (size_t)l * D;
        const float* ge_l = ge + (size_t)l * HE;
        const float* bte_l = betae + (size_t)l * HE;

        k_edgeB<<<EB, 256, 0, stream>>>(hB, ebuf, src, dst, Wni_l, Wfij_l, Wnj_l, attn_l,
                                        eb_l, ebuf, logits);
        k_softmax<HEADS><<<(NN * HEADS + 255) / 256, 256, 0, stream>>>(indptr, esort, logits);
        k_matmul_hp<<<(NN * (D / 4) + 255) / 256, 256, 0, stream>>>(hB, Wn_l, bn_l, hp);
        k_aggregate<HEADS><<<NN, 128, 0, stream>>>(indptr, esort, src, logits, hp, hA);

        hipMemsetAsync(stats, 0, 320 * 4, stream);
        k_bnstats<D><<<1024, D, 0, stream>>>(hA, NN, statsH);
        k_bnstats<HE><<<2048, HE, 0, stream>>>(ebuf, NE, statsE);
        k_bnapply<D><<<(int)(((long)NN * D + 255) / 256), 256, 0, stream>>>(hA, statsH, gn_l,
                                                                            btn_l, hB, NN);
        k_bnapply<HE><<<(int)(((long)NE * HE + 255) / 256), 256, 0, stream>>>(ebuf, statsE,
                                                                              ge_l, bte_l,
                                                                              ebuf, NE);
    }

    k_out<<<(NN + 255) / 256, 256, 0, stream>>>(hB, Wfc, bfc, (float*)d_out);
}

// Round 2
// 4015.881 us; speedup vs baseline: 5.5942x; 5.5942x over previous
//
#include <hip/hip_runtime.h>

#define NN 50000
#define NE 800000
#define D 128
#define HE 32
#define HEADS 4
#define DEPTH 8
#define EPSV 1e-5f
#define SLOPE 0.01f

__device__ __forceinline__ float lrelu(float x) { return x > 0.f ? x : SLOPE * x; }

// ---------- h init: h = concat(Wseq[seq], Wsec[sec]) ----------
__global__ void k_init_h(const int* __restrict__ seq, const int* __restrict__ sec,
                         const float* __restrict__ Wseq, const float* __restrict__ Wsec,
                         float* __restrict__ h) {
    int n = blockIdx.x;
    int d = threadIdx.x;  // 128
    float v = (d < 96) ? Wseq[seq[n] * 96 + d] : Wsec[sec[n] * 32 + (d - 96)];
    h[(size_t)n * D + d] = v;
}

// ---------- CSR build ----------
__global__ void k_count(const int* __restrict__ dst, int* __restrict__ cnt) {
    int e = blockIdx.x * blockDim.x + threadIdx.x;
    if (e < NE) atomicAdd(&cnt[dst[e]], 1);
}

__global__ void k_scan(const int* __restrict__ cnt, int* __restrict__ indptr) {
    __shared__ int sh[257];
    const int T = 256;
    int tid = threadIdx.x;
    int chunk = (NN + T - 1) / T;
    int b = tid * chunk;
    int e = min(b + chunk, NN);
    int s = 0;
    for (int i = b; i < e; i++) s += cnt[i];
    sh[tid] = s;
    __syncthreads();
    if (tid == 0) {
        int run = 0;
        for (int i = 0; i < T; i++) { int v = sh[i]; sh[i] = run; run += v; }
        sh[256] = run;
    }
    __syncthreads();
    int run = sh[tid];
    for (int i = b; i < e; i++) { indptr[i] = run; run += cnt[i]; }
    if (tid == 0) indptr[NN] = sh[256];
}

__global__ void k_scatter(const int* __restrict__ dst, const int* __restrict__ indptr,
                          int* __restrict__ cursor, int* __restrict__ esort) {
    int e = blockIdx.x * blockDim.x + threadIdx.x;
    if (e >= NE) return;
    int dn = dst[e];
    int pos = atomicAdd(&cursor[dn], 1);
    esort[indptr[dn] + pos] = e;
}

// ---------- build permuted (dst-sorted) edge arrays ----------
__global__ void k_permute(const int* __restrict__ esort, const int* __restrict__ src,
                          const int* __restrict__ dst, const float* __restrict__ edge_p,
                          int* __restrict__ src_s, int* __restrict__ dst_s,
                          float* __restrict__ ep_s) {
    int i = blockIdx.x * blockDim.x + threadIdx.x;
    if (i >= NE) return;
    int e = esort[i];
    src_s[i] = src[e];
    dst_s[i] = dst[e];
    ep_s[i] = edge_p[e];
}

// ---------- node projections: ni = h@Wni, nj = h@Wnj (N x 32 each) ----------
__global__ __launch_bounds__(256) void k_proj(const float* __restrict__ h,
                                              const float* __restrict__ Wni,
                                              const float* __restrict__ Wnj,
                                              float* __restrict__ ni, float* __restrict__ nj) {
    int t = blockIdx.x * blockDim.x + threadIdx.x;
    int n = t >> 3;
    int c0 = (t & 7) * 4;
    if (n >= NN) return;
    const float4* h4 = (const float4*)(h + (size_t)n * D);
    float4 ai = make_float4(0.f, 0.f, 0.f, 0.f);
    float4 aj = make_float4(0.f, 0.f, 0.f, 0.f);
    for (int d4 = 0; d4 < D / 4; d4++) {
        float4 hv = h4[d4];
        float hc[4] = {hv.x, hv.y, hv.z, hv.w};
#pragma unroll
        for (int c = 0; c < 4; c++) {
            float v = hc[c];
            float4 wi = *(const float4*)(Wni + (size_t)(4 * d4 + c) * HE + c0);
            float4 wj = *(const float4*)(Wnj + (size_t)(4 * d4 + c) * HE + c0);
            ai.x += v * wi.x; ai.y += v * wi.y; ai.z += v * wi.z; ai.w += v * wi.w;
            aj.x += v * wj.x; aj.y += v * wj.y; aj.z += v * wj.z; aj.w += v * wj.w;
        }
    }
    *(float4*)(ni + (size_t)n * HE + c0) = ai;
    *(float4*)(nj + (size_t)n * HE + c0) = aj;
}

// ---------- layer-0 edge kernel (heads=1, e = scalar edge_p, sorted order) ----------
__global__ __launch_bounds__(256) void k_edge0(
    const float* __restrict__ ep_s, const int* __restrict__ src_s,
    const int* __restrict__ dst_s, const float* __restrict__ ni,
    const float* __restrict__ nj, const float* __restrict__ Wfij,
    const float* __restrict__ attn, const float* __restrict__ ebias,
    float* __restrict__ fout, float* __restrict__ logits) {
    int i = blockIdx.x * blockDim.x + threadIdx.x;
    if (i >= NE) return;
    int sn = src_s[i], dn = dst_s[i];
    float p = ep_s[i];
    const float4* niv = (const float4*)(ni + (size_t)sn * HE);
    const float4* njv = (const float4*)(nj + (size_t)dn * HE);
    float acc[HE];
#pragma unroll
    for (int j = 0; j < 8; j++) {
        float4 a = niv[j];
        float4 b = njv[j];
#pragma unroll
        for (int c = 0; c < 4; c++) {
            int k = 4 * j + c;
            float av = (c == 0) ? a.x : (c == 1) ? a.y : (c == 2) ? a.z : a.w;
            float bv = (c == 0) ? b.x : (c == 1) ? b.y : (c == 2) ? b.z : b.w;
            acc[k] = ebias[k] + p * Wfij[k] + av + bv;
        }
    }
    float lg = 0.f;
#pragma unroll
    for (int k = 0; k < HE; k++) {
        acc[k] = lrelu(acc[k]);
        lg += acc[k] * attn[k];
    }
    float4* fo = (float4*)(fout + (size_t)i * HE);
#pragma unroll
    for (int j = 0; j < 8; j++)
        fo[j] = make_float4(acc[4 * j], acc[4 * j + 1], acc[4 * j + 2], acc[4 * j + 3]);
    logits[i] = lg;
}

// ---------- deep edge kernel (heads=4); fuses prev-layer BN+lrelu on e ----------
template <int FIRST, int LAST>
__global__ __launch_bounds__(256) void k_edgeB(
    const float* __restrict__ e_in, const int* __restrict__ src_s,
    const int* __restrict__ dst_s, const float* __restrict__ ni,
    const float* __restrict__ nj, const float* __restrict__ Wfij,
    const float* __restrict__ attn, const float* __restrict__ ebias,
    const float* __restrict__ scsh,  // [256..287]=scaleE, [288..319]=shiftE (prev layer)
    float* __restrict__ fout, float* __restrict__ logits) {
    int i = blockIdx.x * blockDim.x + threadIdx.x;
    if (i >= NE) return;
    int sn = src_s[i], dn = dst_s[i];
    const float4* niv = (const float4*)(ni + (size_t)sn * HE);
    const float4* njv = (const float4*)(nj + (size_t)dn * HE);
    float acc[HE];
#pragma unroll
    for (int j = 0; j < 8; j++) {
        float4 a = niv[j];
        float4 b = njv[j];
        acc[4 * j + 0] = ebias[4 * j + 0] + a.x + b.x;
        acc[4 * j + 1] = ebias[4 * j + 1] + a.y + b.y;
        acc[4 * j + 2] = ebias[4 * j + 2] + a.z + b.z;
        acc[4 * j + 3] = ebias[4 * j + 3] + a.w + b.w;
    }
    const float4* ein4 = (const float4*)(e_in + (size_t)i * HE);
#pragma unroll
    for (int j = 0; j < 8; j++) {
        float4 ev = ein4[j];
        float ec[4] = {ev.x, ev.y, ev.z, ev.w};
#pragma unroll
        for (int c = 0; c < 4; c++) {
            int de = 4 * j + c;
            float x = ec[c];
            if (!FIRST) x = lrelu(x * scsh[256 + de] + scsh[288 + de]);
            const float* wr = Wfij + (size_t)de * HE;
#pragma unroll
            for (int k = 0; k < HE; k++) acc[k] += x * wr[k];
        }
    }
#pragma unroll
    for (int k = 0; k < HE; k++) acc[k] = lrelu(acc[k]);
    if (!LAST) {
        float4* fo = (float4*)(fout + (size_t)i * HE);
#pragma unroll
        for (int j = 0; j < 8; j++)
            fo[j] = make_float4(acc[4 * j], acc[4 * j + 1], acc[4 * j + 2], acc[4 * j + 3]);
    }
    float lg[HEADS];
#pragma unroll
    for (int hh = 0; hh < HEADS; hh++) {
        float s = 0.f;
#pragma unroll
        for (int j = 0; j < 8; j++) s += acc[hh * 8 + j] * attn[hh * 8 + j];
        lg[hh] = s;
    }
    *(float4*)(logits + (size_t)i * HEADS) = make_float4(lg[0], lg[1], lg[2], lg[3]);
}

// ---------- segment softmax on contiguous (sorted) logits, in-place ----------
template <int H>
__global__ void k_softmax(const int* __restrict__ indptr, float* __restrict__ logits) {
    int t = blockIdx.x * blockDim.x + threadIdx.x;
    int n = t / H;
    int hh = t % H;
    if (n >= NN) return;
    int b = indptr[n], e = indptr[n + 1];
    if (b == e) return;
    float m = -1e30f;
    for (int i = b; i < e; i++) m = fmaxf(m, logits[(size_t)i * H + hh]);
    float s = 0.f;
    for (int i = b; i < e; i++) s += expf(logits[(size_t)i * H + hh] - m);
    float inv = 1.f / s;
    for (int i = b; i < e; i++) {
        size_t idx = (size_t)i * H + hh;
        logits[idx] = expf(logits[idx] - m) * inv;
    }
}

// ---------- hp = h @ W + b  (N x D) ----------
__global__ __launch_bounds__(256) void k_matmul_hp(const float* __restrict__ h,
                                                   const float* __restrict__ W,
                                                   const float* __restrict__ bias,
                                                   float* __restrict__ hp) {
    int t = blockIdx.x * blockDim.x + threadIdx.x;
    int n = t / (D / 4);
    int c0 = (t % (D / 4)) * 4;
    if (n >= NN) return;
    const float* hr = h + (size_t)n * D;
    float4 acc = *(const float4*)(bias + c0);
    for (int d = 0; d < D; d++) {
        float hv = hr[d];
        float4 w = *(const float4*)(W + (size_t)d * D + c0);
        acc.x += hv * w.x; acc.y += hv * w.y; acc.z += hv * w.z; acc.w += hv * w.w;
    }
    *(float4*)(hp + (size_t)n * D + c0) = acc;
}

// ---------- h_out[n][d] = sum over in-edges (sorted) a[i][d/32] * hp[src_s[i]][d] ----------
template <int H>
__global__ void k_aggregate(const int* __restrict__ indptr, const int* __restrict__ src_s,
                            const float* __restrict__ a, const float* __restrict__ hp,
                            float* __restrict__ hacc) {
    int n = blockIdx.x;
    int d = threadIdx.x;  // 128
    int b = indptr[n], e = indptr[n + 1];
    int hh = (H == 1) ? 0 : (d >> 5);
    float acc = 0.f;
    for (int i = b; i < e; i++) {
        float av = a[(size_t)i * H + hh];
        acc += av * hp[(size_t)src_s[i] * D + d];
    }
    hacc[(size_t)n * D + d] = acc;
}

// ---------- batchnorm stats with block-level LDS reduction ----------
template <int C>
__global__ __launch_bounds__(256) void k_bnstats(const float* __restrict__ x, int rows,
                                                 float* __restrict__ sums) {
    const int RPB = 256 / C;
    __shared__ float sh[512];
    int tid = threadIdx.x;
    int d = tid % C;
    int r0 = tid / C;
    float s = 0.f, s2 = 0.f;
    for (long r = (long)blockIdx.x * RPB + r0; r < rows; r += (long)gridDim.x * RPB) {
        float v = x[r * C + d];
        s += v;
        s2 += v * v;
    }
    sh[tid] = s;
    sh[256 + tid] = s2;
    __syncthreads();
    for (int st = 128; st >= C; st >>= 1) {
        if (tid < st) {
            sh[tid] += sh[tid + st];
            sh[256 + tid] += sh[256 + tid + st];
        }
        __syncthreads();
    }
    if (tid < C) {
        atomicAdd(&sums[d], sh[tid]);
        atomicAdd(&sums[C + d], sh[256 + tid]);
    }
}

// ---------- BN scale/shift prep: scsh = [scaleH 128][shiftH 128][scaleE 32][shiftE 32] ----------
__global__ void k_bnprep(const float* __restrict__ sumsH, const float* __restrict__ gH,
                         const float* __restrict__ bH, const float* __restrict__ sumsE,
                         const float* __restrict__ gE, const float* __restrict__ bE,
                         float* __restrict__ scsh, int doE) {
    int t = threadIdx.x;  // 160
    if (t < 128) {
        float mu = sumsH[t] * (1.f / NN);
        float var = sumsH[128 + t] * (1.f / NN) - mu * mu;
        float sc = rsqrtf(var + EPSV) * gH[t];
        scsh[t] = sc;
        scsh[128 + t] = bH[t] - mu * sc;
    } else if (doE) {
        int k = t - 128;
        float mu = sumsE[k] * (1.f / NE);
        float var = sumsE[32 + k] * (1.f / NE) - mu * mu;
        float sc = rsqrtf(var + EPSV) * gE[k];
        scsh[256 + k] = sc;
        scsh[288 + k] = bE[k] - mu * sc;
    }
}

// ---------- h BN apply + lrelu ----------
__global__ void k_bnapply_h(const float* __restrict__ x, const float* __restrict__ scsh,
                            float* __restrict__ y) {
    int t = blockIdx.x * blockDim.x + threadIdx.x;
    if (t >= NN * (D / 4)) return;
    int c0 = (t % (D / 4)) * 4;
    float4 v = ((const float4*)x)[t];
    float4 sc = *(const float4*)(scsh + c0);
    float4 sh = *(const float4*)(scsh + 128 + c0);
    v.x = lrelu(v.x * sc.x + sh.x);
    v.y = lrelu(v.y * sc.y + sh.y);
    v.z = lrelu(v.z * sc.z + sh.z);
    v.w = lrelu(v.w * sc.w + sh.w);
    ((float4*)y)[t] = v;
}

// ---------- out = h @ Wfc + bfc ----------
__global__ void k_out(const float* __restrict__ h, const float* __restrict__ Wfc,
                      const float* __restrict__ bfc, float* __restrict__ out) {
    int n = blockIdx.x * blockDim.x + threadIdx.x;
    if (n >= NN) return;
    const float* hr = h + (size_t)n * D;
    float s = bfc[0];
    for (int d = 0; d < D; d++) s += hr[d] * Wfc[d];
    out[n] = s;
}

extern "C" void kernel_launch(void* const* d_in, const int* in_sizes, int n_in,
                              void* d_out, int out_size, void* d_ws, size_t ws_size,
                              hipStream_t stream) {
    const int* seq = (const int*)d_in[0];
    const int* sec = (const int*)d_in[1];
    const float* edge_p = (const float*)d_in[2];
    const int* src = (const int*)d_in[3];
    const int* dst = (const int*)d_in[4];
    const float* Wseq = (const float*)d_in[5];
    const float* Wsec = (const float*)d_in[6];
    const float* W0_node = (const float*)d_in[7];
    const float* b0_node = (const float*)d_in[8];
    const float* W0_ni = (const float*)d_in[9];
    const float* W0_fij = (const float*)d_in[10];
    const float* W0_nj = (const float*)d_in[11];
    const float* attn0 = (const float*)d_in[12];
    const float* ebias0 = (const float*)d_in[13];
    const float* Wn = (const float*)d_in[14];
    const float* bn = (const float*)d_in[15];
    const float* Wni = (const float*)d_in[16];
    const float* Wfij = (const float*)d_in[17];
    const float* Wnj = (const float*)d_in[18];
    const float* attnB = (const float*)d_in[19];
    const float* ebiasB = (const float*)d_in[20];
    const float* gn = (const float*)d_in[21];
    const float* betan = (const float*)d_in[22];
    const float* ge = (const float*)d_in[23];
    const float* betae = (const float*)d_in[24];
    const float* Wfc = (const float*)d_in[25];
    const float* bfc = (const float*)d_in[26];

    char* p = (char*)d_ws;
    auto alloc = [&](size_t bytes) -> char* {
        char* r = p;
        p += (bytes + 255) & ~(size_t)255;
        return r;
    };
    float* hA = (float*)alloc((size_t)NN * D * 4);     // pre-BN aggregate
    float* hB = (float*)alloc((size_t)NN * D * 4);     // current h
    float* hp = (float*)alloc((size_t)NN * D * 4);
    float* ebuf = (float*)alloc((size_t)NE * HE * 4);  // f (sorted order, in-place)
    float* logits = (float*)alloc((size_t)NE * HEADS * 4);
    float* ni = (float*)alloc((size_t)NN * HE * 4);
    float* nj = (float*)alloc((size_t)NN * HE * 4);
    int* esort = (int*)alloc((size_t)NE * 4);
    int* src_s = (int*)alloc((size_t)NE * 4);
    int* dst_s = (int*)alloc((size_t)NE * 4);
    float* ep_s = (float*)alloc((size_t)NE * 4);
    int* cnt = (int*)alloc((size_t)NN * 4);
    int* cursor = (int*)alloc((size_t)NN * 4);
    int* indptr = (int*)alloc((size_t)(NN + 1) * 4);
    float* sums = (float*)alloc(384 * 4);  // sumsH[256], sumsE[64]
    float* sumsH = sums;
    float* sumsE = sums + 256;
    float* scsh0 = (float*)alloc(320 * 4);
    float* scsh1 = (float*)alloc(320 * 4);

    const int EB = (NE + 255) / 256;  // 3125

    // CSR build + permuted edge arrays
    hipMemsetAsync(cnt, 0, (size_t)NN * 4, stream);
    hipMemsetAsync(cursor, 0, (size_t)NN * 4, stream);
    k_init_h<<<NN, 128, 0, stream>>>(seq, sec, Wseq, Wsec, hB);
    k_count<<<EB, 256, 0, stream>>>(dst, cnt);
    k_scan<<<1, 256, 0, stream>>>(cnt, indptr);
    k_scatter<<<EB, 256, 0, stream>>>(dst, indptr, cursor, esort);
    k_permute<<<EB, 256, 0, stream>>>(esort, src, dst, edge_p, src_s, dst_s, ep_s);

    // ---- layer 0 (heads = 1), no BN ----
    k_proj<<<(NN * 8 + 255) / 256, 256, 0, stream>>>(hB, W0_ni, W0_nj, ni, nj);
    k_edge0<<<EB, 256, 0, stream>>>(ep_s, src_s, dst_s, ni, nj, W0_fij, attn0, ebias0, ebuf,
                                    logits);
    k_softmax<1><<<(NN + 255) / 256, 256, 0, stream>>>(indptr, logits);
    k_matmul_hp<<<(NN * (D / 4) + 255) / 256, 256, 0, stream>>>(hB, W0_node, b0_node, hp);
    k_aggregate<1><<<NN, 128, 0, stream>>>(indptr, src_s, logits, hp, hB);

    // ---- deep layers ----
    for (int l = 0; l < DEPTH; l++) {
        const float* Wn_l = Wn + (size_t)l * D * D;
        const float* bn_l = bn + (size_t)l * D;
        const float* Wni_l = Wni + (size_t)l * D * HE;
        const float* Wfij_l = Wfij + (size_t)l * HE * HE;
        const float* Wnj_l = Wnj + (size_t)l * D * HE;
        const float* attn_l = attnB + (size_t)l * HE;
        const float* eb_l = ebiasB + (size_t)l * HE;
        float* scshPrev = (l & 1) ? scsh0 : scsh1;  // written at end of layer l-1
        float* scshCur = (l & 1) ? scsh1 : scsh0;

        k_proj<<<(NN * 8 + 255) / 256, 256, 0, stream>>>(hB, Wni_l, Wnj_l, ni, nj);
        if (l == 0)
            k_edgeB<1, 0><<<EB, 256, 0, stream>>>(ebuf, src_s, dst_s, ni, nj, Wfij_l, attn_l,
                                                  eb_l, scshPrev, ebuf, logits);
        else if (l == DEPTH - 1)
            k_edgeB<0, 1><<<EB, 256, 0, stream>>>(ebuf, src_s, dst_s, ni, nj, Wfij_l, attn_l,
                                                  eb_l, scshPrev, ebuf, logits);
        else
            k_edgeB<0, 0><<<EB, 256, 0, stream>>>(ebuf, src_s, dst_s, ni, nj, Wfij_l, attn_l,
                                                  eb_l, scshPrev, ebuf, logits);
        k_softmax<HEADS><<<(NN * HEADS + 255) / 256, 256, 0, stream>>>(indptr, logits);
        k_matmul_hp<<<(NN * (D / 4) + 255) / 256, 256, 0, stream>>>(hB, Wn_l, bn_l, hp);
        k_aggregate<HEADS><<<NN, 128, 0, stream>>>(indptr, src_s, logits, hp, hA);

        hipMemsetAsync(sums, 0, 384 * 4, stream);
        k_bnstats<D><<<512, 256, 0, stream>>>(hA, NN, sumsH);
        if (l < DEPTH - 1) k_bnstats<HE><<<1024, 256, 0, stream>>>(ebuf, NE, sumsE);
        k_bnprep<<<1, 160, 0, stream>>>(sumsH, gn + (size_t)l * D, betan + (size_t)l * D,
                                        sumsE, ge + (size_t)l * HE, betae + (size_t)l * HE,
                                        scshCur, l < DEPTH - 1 ? 1 : 0);
        k_bnapply_h<<<(NN * (D / 4) + 255) / 256, 256, 0, stream>>>(hA, scshCur, hB);
    }

    k_out<<<(NN + 255) / 256, 256, 0, stream>>>(hB, Wfc, bfc, (float*)d_out);
}

// Round 3
// 2869.845 us; speedup vs baseline: 7.8281x; 1.3993x over previous
//
#include <hip/hip_runtime.h>

#define NN 50000
#define NE 800000
#define D 128
#define HE 32
#define HEADS 4
#define DEPTH 8
#define EPSV 1e-5f
#define SLOPE 0.01f

__device__ __forceinline__ float lrelu(float x) { return x > 0.f ? x : SLOPE * x; }

// ---------- h init: h = concat(Wseq[seq], Wsec[sec]) ----------
__global__ void k_init_h(const int* __restrict__ seq, const int* __restrict__ sec,
                         const float* __restrict__ Wseq, const float* __restrict__ Wsec,
                         float* __restrict__ h) {
    int n = blockIdx.x;
    int d = threadIdx.x;  // 128
    float v = (d < 96) ? Wseq[seq[n] * 96 + d] : Wsec[sec[n] * 32 + (d - 96)];
    h[(size_t)n * D + d] = v;
}

// ---------- CSR build ----------
__global__ void k_count(const int* __restrict__ dst, int* __restrict__ cnt) {
    int e = blockIdx.x * blockDim.x + threadIdx.x;
    if (e < NE) atomicAdd(&cnt[dst[e]], 1);
}

__global__ void k_scan(const int* __restrict__ cnt, int* __restrict__ indptr) {
    __shared__ int sh[257];
    const int T = 256;
    int tid = threadIdx.x;
    int chunk = (NN + T - 1) / T;
    int b = tid * chunk;
    int e = min(b + chunk, NN);
    int s = 0;
    for (int i = b; i < e; i++) s += cnt[i];
    sh[tid] = s;
    __syncthreads();
    if (tid == 0) {
        int run = 0;
        for (int i = 0; i < T; i++) { int v = sh[i]; sh[i] = run; run += v; }
        sh[256] = run;
    }
    __syncthreads();
    int run = sh[tid];
    for (int i = b; i < e; i++) { indptr[i] = run; run += cnt[i]; }
    if (tid == 0) indptr[NN] = sh[256];
}

__global__ void k_scatter(const int* __restrict__ dst, const int* __restrict__ indptr,
                          int* __restrict__ cursor, int* __restrict__ esort) {
    int e = blockIdx.x * blockDim.x + threadIdx.x;
    if (e >= NE) return;
    int dn = dst[e];
    int pos = atomicAdd(&cursor[dn], 1);
    esort[indptr[dn] + pos] = e;
}

// ---------- build permuted (dst-sorted) edge arrays ----------
__global__ void k_permute(const int* __restrict__ esort, const int* __restrict__ src,
                          const int* __restrict__ dst, const float* __restrict__ edge_p,
                          int* __restrict__ src_s, int* __restrict__ dst_s,
                          float* __restrict__ ep_s) {
    int i = blockIdx.x * blockDim.x + threadIdx.x;
    if (i >= NE) return;
    int e = esort[i];
    src_s[i] = src[e];
    dst_s[i] = dst[e];
    ep_s[i] = edge_p[e];
}

// ---------- fused node kernel: [optional BN+lrelu on input] then
//            hp = h@Wn + b, ni = h@Wni, nj = h@Wnj ----------
// block: 256 threads, 64 rows. thread (rg,cg): rows rg*4..+3;
// cols: hp float4 cg and cg+16; proj float4 cg (ni if cg<8 else nj).
template <int APPLY_BN>
__global__ __launch_bounds__(256) void k_node(
    const float* __restrict__ hin, const float* __restrict__ scsh,
    const float* __restrict__ Wn_, const float* __restrict__ bn_,
    const float* __restrict__ Wni_, const float* __restrict__ Wnj_,
    float* __restrict__ hp, float* __restrict__ ni, float* __restrict__ nj) {
    __shared__ float hs[64][132];  // pad 132: conflict-free b128 row reads
    int tid = threadIdx.x;
    int n0 = blockIdx.x * 64;
#pragma unroll
    for (int k = 0; k < 8; k++) {
        int f = tid + k * 256;
        int r = f >> 5, c4 = f & 31;
        int row = n0 + r;
        if (row >= NN) row = NN - 1;
        float4 v = *(const float4*)(hin + (size_t)row * D + c4 * 4);
        if (APPLY_BN) {
            float4 sc = *(const float4*)(scsh + c4 * 4);
            float4 sh = *(const float4*)(scsh + 128 + c4 * 4);
            v.x = lrelu(v.x * sc.x + sh.x);
            v.y = lrelu(v.y * sc.y + sh.y);
            v.z = lrelu(v.z * sc.z + sh.z);
            v.w = lrelu(v.w * sc.w + sh.w);
        }
        *(float4*)(&hs[r][c4 * 4]) = v;
    }
    __syncthreads();

    int rg = tid >> 4;  // 0..15
    int cg = tid & 15;  // 0..15
    const float* WnA = Wn_ + cg * 4;
    const float* WnB = Wn_ + 64 + cg * 4;
    const float* Wp = ((cg < 8) ? Wni_ : Wnj_) + (cg & 7) * 4;
    float4 bA = *(const float4*)(bn_ + cg * 4);
    float4 bB = *(const float4*)(bn_ + 64 + cg * 4);
    float4 accA[4], accB[4], accC[4];
#pragma unroll
    for (int r = 0; r < 4; r++) {
        accA[r] = bA;
        accB[r] = bB;
        accC[r] = make_float4(0.f, 0.f, 0.f, 0.f);
    }
    for (int d4 = 0; d4 < 32; d4++) {
        float4 hv[4];
#pragma unroll
        for (int r = 0; r < 4; r++) hv[r] = *(const float4*)(&hs[rg * 4 + r][d4 * 4]);
#pragma unroll
        for (int c = 0; c < 4; c++) {
            int d = d4 * 4 + c;
            float4 w0 = *(const float4*)(WnA + (size_t)d * D);
            float4 w1 = *(const float4*)(WnB + (size_t)d * D);
            float4 w2 = *(const float4*)(Wp + (size_t)d * HE);
#pragma unroll
            for (int r = 0; r < 4; r++) {
                float hvc = (c == 0) ? hv[r].x : (c == 1) ? hv[r].y : (c == 2) ? hv[r].z : hv[r].w;
                accA[r].x += hvc * w0.x; accA[r].y += hvc * w0.y;
                accA[r].z += hvc * w0.z; accA[r].w += hvc * w0.w;
                accB[r].x += hvc * w1.x; accB[r].y += hvc * w1.y;
                accB[r].z += hvc * w1.z; accB[r].w += hvc * w1.w;
                accC[r].x += hvc * w2.x; accC[r].y += hvc * w2.y;
                accC[r].z += hvc * w2.z; accC[r].w += hvc * w2.w;
            }
        }
    }
    float* projOut = (cg < 8) ? ni : nj;
    int pc = (cg & 7) * 4;
#pragma unroll
    for (int r = 0; r < 4; r++) {
        int row = n0 + rg * 4 + r;
        if (row < NN) {
            *(float4*)(hp + (size_t)row * D + cg * 4) = accA[r];
            *(float4*)(hp + (size_t)row * D + 64 + cg * 4) = accB[r];
            *(float4*)(projOut + (size_t)row * HE + pc) = accC[r];
        }
    }
}

// ---------- layer-0 edge kernel (heads=1, e = scalar edge_p, sorted order) ----------
__global__ __launch_bounds__(256) void k_edge0(
    const float* __restrict__ ep_s, const int* __restrict__ src_s,
    const int* __restrict__ dst_s, const float* __restrict__ ni,
    const float* __restrict__ nj, const float* __restrict__ Wfij,
    const float* __restrict__ attn, const float* __restrict__ ebias,
    float* __restrict__ fout, float* __restrict__ logits) {
    int i = blockIdx.x * blockDim.x + threadIdx.x;
    if (i >= NE) return;
    int sn = src_s[i], dn = dst_s[i];
    float p = ep_s[i];
    const float4* niv = (const float4*)(ni + (size_t)sn * HE);
    const float4* njv = (const float4*)(nj + (size_t)dn * HE);
    float acc[HE];
#pragma unroll
    for (int j = 0; j < 8; j++) {
        float4 a = niv[j];
        float4 b = njv[j];
        acc[4 * j + 0] = ebias[4 * j + 0] + p * Wfij[4 * j + 0] + a.x + b.x;
        acc[4 * j + 1] = ebias[4 * j + 1] + p * Wfij[4 * j + 1] + a.y + b.y;
        acc[4 * j + 2] = ebias[4 * j + 2] + p * Wfij[4 * j + 2] + a.z + b.z;
        acc[4 * j + 3] = ebias[4 * j + 3] + p * Wfij[4 * j + 3] + a.w + b.w;
    }
    float lg = 0.f;
#pragma unroll
    for (int k = 0; k < HE; k++) {
        acc[k] = lrelu(acc[k]);
        lg += acc[k] * attn[k];
    }
    float4* fo = (float4*)(fout + (size_t)i * HE);
#pragma unroll
    for (int j = 0; j < 8; j++)
        fo[j] = make_float4(acc[4 * j], acc[4 * j + 1], acc[4 * j + 2], acc[4 * j + 3]);
    logits[i] = lg;
}

// ---------- deep edge kernel (heads=4); fuses prev-layer BN+lrelu on e ----------
template <int FIRST, int LAST>
__global__ __launch_bounds__(256) void k_edgeB(
    const float* __restrict__ e_in, const int* __restrict__ src_s,
    const int* __restrict__ dst_s, const float* __restrict__ ni,
    const float* __restrict__ nj, const float* __restrict__ Wfij,
    const float* __restrict__ attn, const float* __restrict__ ebias,
    const float* __restrict__ scsh,  // [256..287]=scaleE, [288..319]=shiftE (prev layer)
    float* __restrict__ fout, float* __restrict__ logits) {
    int i = blockIdx.x * blockDim.x + threadIdx.x;
    if (i >= NE) return;
    int sn = src_s[i], dn = dst_s[i];
    const float4* niv = (const float4*)(ni + (size_t)sn * HE);
    const float4* njv = (const float4*)(nj + (size_t)dn * HE);
    float acc[HE];
#pragma unroll
    for (int j = 0; j < 8; j++) {
        float4 a = niv[j];
        float4 b = njv[j];
        acc[4 * j + 0] = ebias[4 * j + 0] + a.x + b.x;
        acc[4 * j + 1] = ebias[4 * j + 1] + a.y + b.y;
        acc[4 * j + 2] = ebias[4 * j + 2] + a.z + b.z;
        acc[4 * j + 3] = ebias[4 * j + 3] + a.w + b.w;
    }
    const float4* ein4 = (const float4*)(e_in + (size_t)i * HE);
#pragma unroll
    for (int j = 0; j < 8; j++) {
        float4 ev = ein4[j];
        float ec[4] = {ev.x, ev.y, ev.z, ev.w};
#pragma unroll
        for (int c = 0; c < 4; c++) {
            int de = 4 * j + c;
            float x = ec[c];
            if (!FIRST) x = lrelu(x * scsh[256 + de] + scsh[288 + de]);
            const float* wr = Wfij + (size_t)de * HE;
#pragma unroll
            for (int k = 0; k < HE; k++) acc[k] += x * wr[k];
        }
    }
#pragma unroll
    for (int k = 0; k < HE; k++) acc[k] = lrelu(acc[k]);
    if (!LAST) {
        float4* fo = (float4*)(fout + (size_t)i * HE);
#pragma unroll
        for (int j = 0; j < 8; j++)
            fo[j] = make_float4(acc[4 * j], acc[4 * j + 1], acc[4 * j + 2], acc[4 * j + 3]);
    }
    float lg[HEADS];
#pragma unroll
    for (int hh = 0; hh < HEADS; hh++) {
        float s = 0.f;
#pragma unroll
        for (int j = 0; j < 8; j++) s += acc[hh * 8 + j] * attn[hh * 8 + j];
        lg[hh] = s;
    }
    *(float4*)(logits + (size_t)i * HEADS) = make_float4(lg[0], lg[1], lg[2], lg[3]);
}

// ---------- segment softmax on contiguous (sorted) logits, in-place ----------
template <int H>
__global__ void k_softmax(const int* __restrict__ indptr, float* __restrict__ logits) {
    int t = blockIdx.x * blockDim.x + threadIdx.x;
    int n = t / H;
    int hh = t % H;
    if (n >= NN) return;
    int b = indptr[n], e = indptr[n + 1];
    if (b == e) return;
    float m = -1e30f;
    for (int i = b; i < e; i++) m = fmaxf(m, logits[(size_t)i * H + hh]);
    float s = 0.f;
    for (int i = b; i < e; i++) s += expf(logits[(size_t)i * H + hh] - m);
    float inv = 1.f / s;
    for (int i = b; i < e; i++) {
        size_t idx = (size_t)i * H + hh;
        logits[idx] = expf(logits[idx] - m) * inv;
    }
}

// ---------- h_out[n][d] = sum over in-edges (sorted) a[i][d/32] * hp[src_s[i]][d] ----------
template <int H>
__global__ __launch_bounds__(256) void k_aggregate(const int* __restrict__ indptr,
                                                   const int* __restrict__ src_s,
                                                   const float* __restrict__ a,
                                                   const float* __restrict__ hp,
                                                   float* __restrict__ hacc) {
    int n = blockIdx.x * 2 + (threadIdx.x >> 7);
    if (n >= NN) return;
    int d = threadIdx.x & 127;
    int b = indptr[n], e = indptr[n + 1];
    int hh = (H == 1) ? 0 : (d >> 5);
    float acc = 0.f;
#pragma unroll 4
    for (int i = b; i < e; i++) {
        acc += a[(size_t)i * H + hh] * hp[(size_t)src_s[i] * D + d];
    }
    hacc[(size_t)n * D + d] = acc;
}

// ---------- batchnorm stats with block-level LDS reduction ----------
template <int C>
__global__ __launch_bounds__(256) void k_bnstats(const float* __restrict__ x, int rows,
                                                 float* __restrict__ sums) {
    const int RPB = 256 / C;
    __shared__ float sh[512];
    int tid = threadIdx.x;
    int d = tid % C;
    int r0 = tid / C;
    float s = 0.f, s2 = 0.f;
    for (long r = (long)blockIdx.x * RPB + r0; r < rows; r += (long)gridDim.x * RPB) {
        float v = x[r * C + d];
        s += v;
        s2 += v * v;
    }
    sh[tid] = s;
    sh[256 + tid] = s2;
    __syncthreads();
    for (int st = 128; st >= C; st >>= 1) {
        if (tid < st) {
            sh[tid] += sh[tid + st];
            sh[256 + tid] += sh[256 + tid + st];
        }
        __syncthreads();
    }
    if (tid < C) {
        atomicAdd(&sums[d], sh[tid]);
        atomicAdd(&sums[C + d], sh[256 + tid]);
    }
}

// ---------- BN scale/shift prep: scsh = [scaleH 128][shiftH 128][scaleE 32][shiftE 32] ----------
__global__ void k_bnprep(const float* __restrict__ sumsH, const float* __restrict__ gH,
                         const float* __restrict__ bH, const float* __restrict__ sumsE,
                         const float* __restrict__ gE, const float* __restrict__ bE,
                         float* __restrict__ scsh, int doE) {
    int t = threadIdx.x;  // 160
    if (t < 128) {
        float mu = sumsH[t] * (1.f / NN);
        float var = sumsH[128 + t] * (1.f / NN) - mu * mu;
        float sc = rsqrtf(var + EPSV) * gH[t];
        scsh[t] = sc;
        scsh[128 + t] = bH[t] - mu * sc;
    } else if (doE) {
        int k = t - 128;
        float mu = sumsE[k] * (1.f / NE);
        float var = sumsE[32 + k] * (1.f / NE) - mu * mu;
        float sc = rsqrtf(var + EPSV) * gE[k];
        scsh[256 + k] = sc;
        scsh[288 + k] = bE[k] - mu * sc;
    }
}

// ---------- out = lrelu(BN(h)) @ Wfc + bfc ----------
__global__ void k_out(const float* __restrict__ h, const float* __restrict__ scsh,
                      const float* __restrict__ Wfc, const float* __restrict__ bfc,
                      float* __restrict__ out) {
    int n = blockIdx.x * blockDim.x + threadIdx.x;
    if (n >= NN) return;
    const float* hr = h + (size_t)n * D;
    float s = bfc[0];
    for (int d = 0; d < D; d++) {
        float v = lrelu(hr[d] * scsh[d] + scsh[128 + d]);
        s += v * Wfc[d];
    }
    out[n] = s;
}

extern "C" void kernel_launch(void* const* d_in, const int* in_sizes, int n_in,
                              void* d_out, int out_size, void* d_ws, size_t ws_size,
                              hipStream_t stream) {
    const int* seq = (const int*)d_in[0];
    const int* sec = (const int*)d_in[1];
    const float* edge_p = (const float*)d_in[2];
    const int* src = (const int*)d_in[3];
    const int* dst = (const int*)d_in[4];
    const float* Wseq = (const float*)d_in[5];
    const float* Wsec = (const float*)d_in[6];
    const float* W0_node = (const float*)d_in[7];
    const float* b0_node = (const float*)d_in[8];
    const float* W0_ni = (const float*)d_in[9];
    const float* W0_fij = (const float*)d_in[10];
    const float* W0_nj = (const float*)d_in[11];
    const float* attn0 = (const float*)d_in[12];
    const float* ebias0 = (const float*)d_in[13];
    const float* Wn = (const float*)d_in[14];
    const float* bn = (const float*)d_in[15];
    const float* Wni = (const float*)d_in[16];
    const float* Wfij = (const float*)d_in[17];
    const float* Wnj = (const float*)d_in[18];
    const float* attnB = (const float*)d_in[19];
    const float* ebiasB = (const float*)d_in[20];
    const float* gn = (const float*)d_in[21];
    const float* betan = (const float*)d_in[22];
    const float* ge = (const float*)d_in[23];
    const float* betae = (const float*)d_in[24];
    const float* Wfc = (const float*)d_in[25];
    const float* bfc = (const float*)d_in[26];

    char* p = (char*)d_ws;
    auto alloc = [&](size_t bytes) -> char* {
        char* r = p;
        p += (bytes + 255) & ~(size_t)255;
        return r;
    };
    float* hA = (float*)alloc((size_t)NN * D * 4);
    float* hB = (float*)alloc((size_t)NN * D * 4);
    float* hp = (float*)alloc((size_t)NN * D * 4);
    float* ebuf = (float*)alloc((size_t)NE * HE * 4);  // f (sorted order, in-place)
    float* logits = (float*)alloc((size_t)NE * HEADS * 4);
    float* ni = (float*)alloc((size_t)NN * HE * 4);
    float* nj = (float*)alloc((size_t)NN * HE * 4);
    int* esort = (int*)alloc((size_t)NE * 4);
    int* src_s = (int*)alloc((size_t)NE * 4);
    int* dst_s = (int*)alloc((size_t)NE * 4);
    float* ep_s = (float*)alloc((size_t)NE * 4);
    int* cnt = (int*)alloc((size_t)NN * 4);
    int* cursor = (int*)alloc((size_t)NN * 4);
    int* indptr = (int*)alloc((size_t)(NN + 1) * 4);
    float* sums = (float*)alloc(384 * 4);  // sumsH[256], sumsE[64]
    float* sumsH = sums;
    float* sumsE = sums + 256;
    float* scsh0 = (float*)alloc(320 * 4);
    float* scsh1 = (float*)alloc(320 * 4);

    const int EB = (NE + 255) / 256;    // 3125
    const int NB64 = (NN + 63) / 64;    // 782

    // CSR build + permuted edge arrays
    hipMemsetAsync(cnt, 0, (size_t)NN * 4, stream);
    hipMemsetAsync(cursor, 0, (size_t)NN * 4, stream);
    k_init_h<<<NN, 128, 0, stream>>>(seq, sec, Wseq, Wsec, hB);
    k_count<<<EB, 256, 0, stream>>>(dst, cnt);
    k_scan<<<1, 256, 0, stream>>>(cnt, indptr);
    k_scatter<<<EB, 256, 0, stream>>>(dst, indptr, cursor, esort);
    k_permute<<<EB, 256, 0, stream>>>(esort, src, dst, edge_p, src_s, dst_s, ep_s);

    // ---- layer 0 (heads = 1), no BN ----
    k_node<0><<<NB64, 256, 0, stream>>>(hB, scsh0, W0_node, b0_node, W0_ni, W0_nj, hp, ni, nj);
    k_edge0<<<EB, 256, 0, stream>>>(ep_s, src_s, dst_s, ni, nj, W0_fij, attn0, ebias0, ebuf,
                                    logits);
    k_softmax<1><<<(NN + 255) / 256, 256, 0, stream>>>(indptr, logits);
    k_aggregate<1><<<(NN + 1) / 2, 256, 0, stream>>>(indptr, src_s, logits, hp, hA);

    // ---- deep layers (input hA for l=0; ping-pong) ----
    for (int l = 0; l < DEPTH; l++) {
        const float* Wn_l = Wn + (size_t)l * D * D;
        const float* bn_l = bn + (size_t)l * D;
        const float* Wni_l = Wni + (size_t)l * D * HE;
        const float* Wfij_l = Wfij + (size_t)l * HE * HE;
        const float* Wnj_l = Wnj + (size_t)l * D * HE;
        const float* attn_l = attnB + (size_t)l * HE;
        const float* eb_l = ebiasB + (size_t)l * HE;
        float* scshPrev = (l & 1) ? scsh0 : scsh1;
        float* scshCur = (l & 1) ? scsh1 : scsh0;
        float* hIn = (l & 1) ? hB : hA;
        float* hOut = (l & 1) ? hA : hB;

        if (l == 0)
            k_node<0><<<NB64, 256, 0, stream>>>(hIn, scshPrev, Wn_l, bn_l, Wni_l, Wnj_l, hp,
                                                ni, nj);
        else
            k_node<1><<<NB64, 256, 0, stream>>>(hIn, scshPrev, Wn_l, bn_l, Wni_l, Wnj_l, hp,
                                                ni, nj);

        if (l == 0)
            k_edgeB<1, 0><<<EB, 256, 0, stream>>>(ebuf, src_s, dst_s, ni, nj, Wfij_l, attn_l,
                                                  eb_l, scshPrev, ebuf, logits);
        else if (l == DEPTH - 1)
            k_edgeB<0, 1><<<EB, 256, 0, stream>>>(ebuf, src_s, dst_s, ni, nj, Wfij_l, attn_l,
                                                  eb_l, scshPrev, ebuf, logits);
        else
            k_edgeB<0, 0><<<EB, 256, 0, stream>>>(ebuf, src_s, dst_s, ni, nj, Wfij_l, attn_l,
                                                  eb_l, scshPrev, ebuf, logits);
        k_softmax<HEADS><<<(NN * HEADS + 255) / 256, 256, 0, stream>>>(indptr, logits);
        k_aggregate<HEADS><<<(NN + 1) / 2, 256, 0, stream>>>(indptr, src_s, logits, hp, hOut);

        hipMemsetAsync(sums, 0, 384 * 4, stream);
        k_bnstats<D><<<512, 256, 0, stream>>>(hOut, NN, sumsH);
        if (l < DEPTH - 1) k_bnstats<HE><<<1024, 256, 0, stream>>>(ebuf, NE, sumsE);
        k_bnprep<<<1, 160, 0, stream>>>(sumsH, gn + (size_t)l * D, betan + (size_t)l * D,
                                        sumsE, ge + (size_t)l * HE, betae + (size_t)l * HE,
                                        scshCur, l < DEPTH - 1 ? 1 : 0);
    }

    // final h is in hA (l=7 wrote hOut=hA); BN of layer 7 is in scsh1
    k_out<<<(NN + 255) / 256, 256, 0, stream>>>(hA, scsh1, Wfc, bfc, (float*)d_out);
}